// Round 18
// baseline (1948.818 us; speedup 1.0000x reference)
//
#include <hip/hip_runtime.h>
#include <math.h>

#define N_NODES 20000
#define T_TYPES 4
#define H_DIM   256
#define E_EDGES 160000
#define EK_EDGES 40000
#define CH_EDGE 40000
#define BCAP    32

typedef __attribute__((ext_vector_type(8))) short short8v;
typedef __attribute__((ext_vector_type(8))) unsigned short ushort8v;
typedef __attribute__((ext_vector_type(4))) float f32x4;

__device__ __forceinline__ float silu_f(float x) {
    return x / (1.0f + __expf(-x));
}
__device__ __forceinline__ float b2f(unsigned short u) {
    union { unsigned int i; float f; } v; v.i = ((unsigned int)u) << 16; return v.f;
}
__device__ __forceinline__ unsigned short f2b(float f) {
    union { unsigned int i; float f; } v; v.f = f;
    unsigned int r = v.i + 0x7FFF + ((v.i >> 16) & 1);
    return (unsigned short)(r >> 16);
}

#if __has_builtin(__builtin_amdgcn_global_load_lds)
#define HAS_GLL 1
#define GLOAD16(g, l) __builtin_amdgcn_global_load_lds( \
    (const __attribute__((address_space(1))) void*)(g), \
    (__attribute__((address_space(3))) void*)(l), 16, 0, 0)
#else
#define HAS_GLL 0
#endif

// ---------------- weight transpose+convert: W [K,N] f32 -> Wt [N,K] bf16 -----
__global__ __launch_bounds__(256) void wtrans_kernel(const float* __restrict__ W,
    unsigned short* __restrict__ Wt, int K, int N, long sW, long sWt)
{
    __shared__ float tile[32][33];
    const float* Wz = W + (size_t)blockIdx.z * sW;
    unsigned short* Wtz = Wt + (size_t)blockIdx.z * sWt;
    int tx = threadIdx.x & 31, ty = threadIdx.x >> 5;
    #pragma unroll
    for (int r = ty; r < 32; r += 8) {
        int gr = blockIdx.y * 32 + r, gc = blockIdx.x * 32 + tx;
        tile[r][tx] = Wz[(size_t)gr * N + gc];
    }
    __syncthreads();
    #pragma unroll
    for (int r = ty; r < 32; r += 8) {
        int gn = blockIdx.x * 32 + r, gk = blockIdx.y * 32 + tx;
        Wtz[(size_t)gn * K + gk] = f2b(tile[tx][r]);
    }
}

// ---------------- concat q/k/v biases into one f32[768] ----------------------
__global__ void concat_bias(const float* __restrict__ bq, const float* __restrict__ bk,
    const float* __restrict__ bv, float* __restrict__ b768)
{
    int i = threadIdx.x;
    b768[i] = (i < 256) ? bq[i] : (i < 512 ? bk[i - 256] : bv[i - 512]);
}

// ---------------- node_emb -> bf16 ------------------------------------------
__global__ __launch_bounds__(256) void ne_kernel(const float* __restrict__ h,
    const float* __restrict__ nc_w, const float* __restrict__ nc_b,
    unsigned short* __restrict__ neb)
{
    int idx = blockIdx.x * 256 + threadIdx.x;         // per 4 features
    if (idx >= N_NODES * 64) return;
    int n = idx >> 6, f4 = (idx & 63) * 4;
    const float* hp = h + (size_t)n * 1024 + f4;
    float4 a = *(const float4*)hp;
    float4 b = *(const float4*)(hp + 256);
    float4 c = *(const float4*)(hp + 512);
    float4 d = *(const float4*)(hp + 768);
    float w0 = nc_w[0], w1 = nc_w[1], w2 = nc_w[2], w3 = nc_w[3], bb = nc_b[0];
    ushort4 o;
    o.x = f2b(a.x * w0 + b.x * w1 + c.x * w2 + d.x * w3 + bb);
    o.y = f2b(a.y * w0 + b.y * w1 + c.y * w2 + d.y * w3 + bb);
    o.z = f2b(a.z * w0 + b.z * w1 + c.z * w2 + d.z * w3 + bb);
    o.w = f2b(a.w * w0 + b.w * w1 + c.w * w2 + d.w * w3 + bb);
    *(ushort4*)(neb + (size_t)n * 256 + f4) = o;
}

// ---------------- y1 = silu(P[src] + Q[tgt] + b1), P/Q f32 -> y1 bf16 --------
__global__ __launch_bounds__(256) void y1_kernel(const float* __restrict__ P,
    const float* __restrict__ Q, const float* __restrict__ b1,
    const int* __restrict__ eidx, int base, unsigned short* __restrict__ y1)
{
    int idx = blockIdx.x * 256 + threadIdx.x;       // per 8 outputs
    int row = idx / 96, g = idx - row * 96;         // 768/8 = 96 groups
    int e = base + row;
    int src = eidx[e], tgt = eidx[E_EDGES + e];
    const float* pp = P + (size_t)src * 768 + g * 8;
    const float* qq = Q + (size_t)tgt * 768 + g * 8;
    float4 pa = *(const float4*)pp, pb4 = *(const float4*)(pp + 4);
    float4 qa = *(const float4*)qq, qb4 = *(const float4*)(qq + 4);
    float4 ba = *(const float4*)(b1 + g * 8), bb4 = *(const float4*)(b1 + g * 8 + 4);
    ushort8v o;
    o[0] = f2b(silu_f(pa.x + qa.x + ba.x));
    o[1] = f2b(silu_f(pa.y + qa.y + ba.y));
    o[2] = f2b(silu_f(pa.z + qa.z + ba.z));
    o[3] = f2b(silu_f(pa.w + qa.w + ba.w));
    o[4] = f2b(silu_f(pb4.x + qb4.x + bb4.x));
    o[5] = f2b(silu_f(pb4.y + qb4.y + bb4.y));
    o[6] = f2b(silu_f(pb4.z + qb4.z + bb4.z));
    o[7] = f2b(silu_f(pb4.w + qb4.w + bb4.w));
    *(ushort8v*)(y1 + (size_t)row * 768 + g * 8) = o;
}

// ---------------- bf16 MFMA GEMM (R14: 8-wave 128x128, 2-slot vmcnt) ---------
// R18 delta: optional Hf fuse input (hid = silu(v)+Hf) in the epilogue, used
// only by conv-L4 to fold hid_kernel away. Everything else is R14 verbatim.
__global__ __launch_bounds__(512, 6) void mfma_gemm(
    const unsigned short* __restrict__ A, long lda, long zsA,
    const unsigned short* __restrict__ Bt, long zsW,
    const float* __restrict__ bias, long zsBias,
    const float* __restrict__ Rf, long ldr, long zsR,
    const float* __restrict__ Hf, long ldh, long zsH,
    float* __restrict__ Cf, unsigned short* __restrict__ Cb, long ldc, long zsC,
    int M, int K, int Nc, int act)
{
    // 2 slots x (A 4096 + B 4096 ushorts) = 32 KB; epilogue [32][136] aliases slot0
    __shared__ unsigned short smem[16384];

    int tid = threadIdx.x;
    int wid = tid >> 6, lane = tid & 63;
    int wr = wid >> 1, wc = wid & 1;                // wave sub-tile (32r x 64c)

    // bijective XCD-chunked swizzle (m204)
    int nwg = gridDim.x * gridDim.y;
    int lin = blockIdx.y * gridDim.x + blockIdx.x;
    int q = nwg >> 3, r8 = nwg & 7, xcd = lin & 7, jj = lin >> 3;
    int g = (xcd < r8 ? xcd * (q + 1) : r8 * (q + 1) + (xcd - r8) * q) + jj;
    int row0 = (g / gridDim.x) * 128, col0 = (g % gridDim.x) * 128;

    int z = blockIdx.z;
    const unsigned short* Btz = Bt + (size_t)z * zsW;
    const float* biasz = bias ? bias + (size_t)z * zsBias : nullptr;
    const float* Rfz = Rf ? Rf + (size_t)z * zsR : nullptr;
    const float* Hfz = Hf ? Hf + (size_t)z * zsH : nullptr;
    float* Cfz = Cf ? Cf + (size_t)z * zsC : nullptr;
    unsigned short* Cbz = Cb ? Cb + (size_t)z * zsC : nullptr;

    int kb = tid >> 7;                              // k-chunk 0..3 (8 elems each)
    int idx = tid & 127;                            // row (A) / col (B)

    const unsigned short* Ag0 = A + (size_t)z * zsA + (size_t)(row0 + idx) * lda + kb * 8;
    const unsigned short* Bg0 = Btz + (size_t)(col0 + idx) * K + kb * 8;

    f32x4 acc[2][4];
    #pragma unroll
    for (int i = 0; i < 2; i++)
        #pragma unroll
        for (int j = 0; j < 4; j++)
            acc[i][j] = (f32x4){0.f, 0.f, 0.f, 0.f};

    int nt = K / 32;
    int lds_dst = kb * 1024 + idx * 8;              // [kb][idx][8]

#if HAS_GLL
#define STAGE(s, k0) do { \
    GLOAD16(Ag0 + (k0), &smem[(s) * 8192 + lds_dst]); \
    GLOAD16(Bg0 + (k0), &smem[(s) * 8192 + 4096 + lds_dst]); \
} while (0)

    STAGE(0, 0);
    for (int t = 0; t < nt; ++t) {
        if (t + 1 < nt) {
            STAGE((t + 1) & 1, (t + 1) * 32);
            asm volatile("s_waitcnt vmcnt(2)" ::: "memory");
        } else {
            asm volatile("s_waitcnt vmcnt(0)" ::: "memory");
        }
        __builtin_amdgcn_sched_barrier(0);
        __builtin_amdgcn_s_barrier();
        __builtin_amdgcn_sched_barrier(0);
        const unsigned short* Asb = &smem[(t & 1) * 8192];
        const unsigned short* Bsb = Asb + 4096;
        short8v af[2], bfr[4];
        int kb4 = (lane >> 4) * 1024;
        int lr = lane & 15;
        #pragma unroll
        for (int mi = 0; mi < 2; mi++)
            af[mi] = *(const short8v*)&Asb[kb4 + (wr * 32 + mi * 16 + lr) * 8];
        #pragma unroll
        for (int ni = 0; ni < 4; ni++)
            bfr[ni] = *(const short8v*)&Bsb[kb4 + (wc * 64 + ni * 16 + lr) * 8];
        #pragma unroll
        for (int mi = 0; mi < 2; mi++)
            #pragma unroll
            for (int ni = 0; ni < 4; ni++)
                acc[mi][ni] = __builtin_amdgcn_mfma_f32_16x16x32_bf16(
                    af[mi], bfr[ni], acc[mi][ni], 0, 0, 0);
        // trailing barrier: protects slot (t&1) from iter t+2's STAGE overwrite
        __builtin_amdgcn_sched_barrier(0);
        __builtin_amdgcn_s_barrier();
        __builtin_amdgcn_sched_barrier(0);
    }
#undef STAGE
#else
    for (int t = 0; t < nt; ++t) {
        int k0 = t * 32;
        __syncthreads();
        *(ushort8v*)&smem[lds_dst] = *(const ushort8v*)(Ag0 + k0);
        *(ushort8v*)&smem[4096 + lds_dst] = *(const ushort8v*)(Bg0 + k0);
        __syncthreads();
        short8v af[2], bfr[4];
        int kb4 = (lane >> 4) * 1024;
        int lr = lane & 15;
        #pragma unroll
        for (int mi = 0; mi < 2; mi++)
            af[mi] = *(const short8v*)&smem[kb4 + (wr * 32 + mi * 16 + lr) * 8];
        #pragma unroll
        for (int ni = 0; ni < 4; ni++)
            bfr[ni] = *(const short8v*)&smem[4096 + kb4 + (wc * 64 + ni * 16 + lr) * 8];
        #pragma unroll
        for (int mi = 0; mi < 2; mi++)
            #pragma unroll
            for (int ni = 0; ni < 4; ni++)
                acc[mi][ni] = __builtin_amdgcn_mfma_f32_16x16x32_bf16(
                    af[mi], bfr[ni], acc[mi][ni], 0, 0, 0);
    }
    __syncthreads();
#endif

    if (Cbz) {
        // bf16 output via LDS transpose -> ushort8 coalesced stores.
        #pragma unroll
        for (int rg = 0; rg < 4; rg++) {
            __syncthreads();
            if (wr == rg) {
                #pragma unroll
                for (int ni = 0; ni < 4; ni++) {
                    int col = wc * 64 + ni * 16 + (lane & 15);
                    float bv = biasz ? biasz[col0 + col] : 0.f;
                    #pragma unroll
                    for (int mi = 0; mi < 2; mi++) {
                        #pragma unroll
                        for (int rr = 0; rr < 4; rr++) {
                            int lrow = mi * 16 + (lane >> 4) * 4 + rr;   // 0..31
                            int grow = row0 + rg * 32 + lrow;
                            float v = acc[mi][ni][rr] + bv;
                            if (act) v = silu_f(v);
                            if (grow < M) {
                                size_t off = (size_t)grow * ldc + col0 + col;
                                if (Rfz) v += Rfz[(size_t)grow * ldr + col0 + col];
                                if (Hfz) v = silu_f(v) + Hfz[(size_t)grow * ldh + col0 + col];
                                if (Cfz) Cfz[off] = v;
                            }
                            smem[lrow * 136 + col] = f2b(v);
                        }
                    }
                }
            }
            __syncthreads();
            int rrow = tid >> 4, grp = tid & 15;
            int grow = row0 + rg * 32 + rrow;
            if (grow < M)
                *(ushort8v*)(Cbz + (size_t)grow * ldc + col0 + grp * 8) =
                    *(const ushort8v*)&smem[rrow * 136 + grp * 8];
        }
    } else {
        #pragma unroll
        for (int ni = 0; ni < 4; ni++) {
            int col = col0 + wc * 64 + ni * 16 + (lane & 15);
            float bv = biasz ? biasz[col] : 0.f;
            #pragma unroll
            for (int mi = 0; mi < 2; mi++) {
                #pragma unroll
                for (int rr = 0; rr < 4; rr++) {
                    int grow = row0 + wr * 32 + mi * 16 + (lane >> 4) * 4 + rr;
                    if (grow < M) {
                        float v = acc[mi][ni][rr] + bv;
                        if (act) v = silu_f(v);
                        size_t off = (size_t)grow * ldc + col;
                        if (Rfz) v += Rfz[(size_t)grow * ldr + col];
                        if (Hfz) v = silu_f(v) + Hfz[(size_t)grow * ldh + col];
                        Cfz[off] = v;
                    }
                }
            }
        }
    }
}

// ---------------- GINE bucket build: cnt/slots keyed by (t, dst) -------------
__global__ __launch_bounds__(256) void gine_hist(const int* __restrict__ eidx,
    const int* __restrict__ emask, int* __restrict__ cnt, int* __restrict__ slots)
{
    int idx = blockIdx.x * 256 + threadIdx.x;       // [0, T*EK)
    int t = idx / EK_EDGES;
    int em = emask[idx];
    int dst = eidx[E_EDGES + em];
    int tn = t * N_NODES + dst;
    int pos = atomicAdd(&cnt[tn], 1);
    if (pos < BCAP) slots[tn * BCAP + pos] = em;
}

// ---------------- GINE gather: z[t,n,:] = xb + sum silu(h[src]+mij[em]) ------
__global__ __launch_bounds__(256) void gine_gather(
    const float* __restrict__ h, const float* __restrict__ mij,
    const int* __restrict__ eidx, const int* __restrict__ cnt,
    const int* __restrict__ slots, float* __restrict__ zf,
    unsigned short* __restrict__ zb)
{
    int tn = blockIdx.x * 4 + (threadIdx.x >> 6);
    int lane = threadIdx.x & 63;
    int t = tn / N_NODES, n = tn - t * N_NODES;
    int f = lane * 4;
    int deg = cnt[tn]; if (deg > BCAP) deg = BCAP;
    float4 acc = *(const float4*)(h + (size_t)n * 1024 + t * 256 + f);   // xb
    for (int j = 0; j < deg; j++) {
        int em = slots[tn * BCAP + j];
        int src = eidx[em];
        float4 hv = *(const float4*)(h + (size_t)src * 1024 + t * 256 + f);
        float4 mv = *(const float4*)(mij + (size_t)em * 256 + f);
        acc.x += silu_f(hv.x + mv.x);
        acc.y += silu_f(hv.y + mv.y);
        acc.z += silu_f(hv.z + mv.z);
        acc.w += silu_f(hv.w + mv.w);
    }
    *(float4*)(zf + (size_t)tn * 256 + f) = acc;
    ushort4 o;
    o.x = f2b(acc.x); o.y = f2b(acc.y); o.z = f2b(acc.z); o.w = f2b(acc.w);
    *(ushort4*)(zb + (size_t)tn * 256 + f) = o;
}

// ---------------- attention core on interleaved qkv [80000, 768] bf16 --------
__global__ __launch_bounds__(256) void attn_core(unsigned short* __restrict__ qkv)
{
    int tid = threadIdx.x;
    int n = blockIdx.x * 2 + (tid >> 7);
    int local = tid & 127, hh = local >> 2, i = local & 3;
    size_t rb = (size_t)n * 4 * 768;
    size_t qoff = rb + (size_t)i * 768 + hh * 8;
    ushort8v qv = *(const ushort8v*)(qkv + qoff);
    float q[8];
    #pragma unroll
    for (int d = 0; d < 8; d++) q[d] = b2f(qv[d]);
    const float scale = 0.35355339059327373f;   // 1/sqrt(8)
    float s[4];
    #pragma unroll
    for (int j = 0; j < 4; j++) {
        ushort8v kv = *(const ushort8v*)(qkv + rb + (size_t)j * 768 + 256 + hh * 8);
        float acc = 0.f;
        #pragma unroll
        for (int d = 0; d < 8; d++) acc += q[d] * b2f(kv[d]);
        s[j] = acc * scale;
    }
    float m = fmaxf(fmaxf(s[0], s[1]), fmaxf(s[2], s[3]));
    float e[4], sum = 0.f;
    #pragma unroll
    for (int j = 0; j < 4; j++) { e[j] = __expf(s[j] - m); sum += e[j]; }
    float inv = 1.0f / sum;
    float o[8] = {};
    #pragma unroll
    for (int j = 0; j < 4; j++) {
        ushort8v vv = *(const ushort8v*)(qkv + rb + (size_t)j * 768 + 512 + hh * 8);
        float p = e[j] * inv;
        #pragma unroll
        for (int d = 0; d < 8; d++) o[d] += p * b2f(vv[d]);
    }
    ushort8v ov;
    #pragma unroll
    for (int d = 0; d < 8; d++) ov[d] = f2b(o[d]);
    *(ushort8v*)(qkv + qoff) = ov;
}

// =============================================================================
extern "C" void kernel_launch(void* const* d_in, const int* in_sizes, int n_in,
                              void* d_out, int out_size, void* d_ws, size_t ws_size,
                              hipStream_t stream)
{
    (void)in_sizes; (void)n_in; (void)out_size; (void)ws_size;
    const float* h     = (const float*)d_in[0];
    const int*   eidx  = (const int*)d_in[1];
    const int*   emask = (const int*)d_in[2];
    const float* nc_w  = (const float*)d_in[3];
    const float* nc_b  = (const float*)d_in[4];
    const float* em_w1 = (const float*)d_in[5];
    const float* em_b1 = (const float*)d_in[6];
    const float* em_w2 = (const float*)d_in[7];
    const float* em_b2 = (const float*)d_in[8];
    const float* em_w3 = (const float*)d_in[9];
    const float* em_b3 = (const float*)d_in[10];
    const float* conv_w = (const float*)d_in[11];
    const float* conv_b = (const float*)d_in[12];
    const float* wq = (const float*)d_in[13]; const float* bq = (const float*)d_in[14];
    const float* wk = (const float*)d_in[15]; const float* bk = (const float*)d_in[16];
    const float* wv = (const float*)d_in[17]; const float* bv = (const float*)d_in[18];
    const float* wo = (const float*)d_in[19]; const float* bo = (const float*)d_in[20];

    float* out = (float*)d_out;                                   // [80000,256] f32
    float* mij = out + (size_t)20480000;                          // [160000,256] f32

    // ---- workspace arena (bytes); peak 188.78 MB ----
    char* w = (char*)d_ws;
    // edge phase
    unsigned short* y1  = (unsigned short*)w;                     // [0, 61.44M)
    unsigned short* ch2 = (unsigned short*)(w + 61440000);        // [61.44M, 102.4M)
    float*          Qf  = (float*)(w + 102400000);                // [102.4M, 163.84M)
    int*            cnt   = (int*)(w + 163840000);                // [163.84M, 164.16M)
    int*            slots = (int*)(w + 164160000);                // [164.16M, 174.4M)
    // GINE / conv phase (cnt/slots consumed by gine_gather before conv writes)
    float*          zf  = (float*)w;                              // [0, 81.92M)
    unsigned short* zb  = (unsigned short*)(w + 81920000);        // [81.92M, 122.88M)
    float*          p1f = (float*)(w + 122880000);                // [122.88M, 163.84M)
    unsigned short* p1b = (unsigned short*)(w + 163840000);       // [163.84M, 184.32M)
    // persistent weights
    unsigned short* wts = (unsigned short*)(w + 184320000);       // 4.46 MB
    float*          bias768 = (float*)(w + 188780032);            // 3 KB
    // attention phase (R18): hidb written at conv-L4 into zf-p0's region
    // (dead after p0-L1; p1 reads only [40.96,81.92M)); qkv after conv.
    unsigned short* hidb = (unsigned short*)w;                    // [0, 40.96M)
    unsigned short* qkv  = (unsigned short*)(w + 40960000);       // [40.96M, 163.84M)

    unsigned short* w1pt  = wts;                    // [768,256]  (W1 rows 0..255)^T
    unsigned short* w1qt  = wts + 196608;           // [768,256]  (W1 rows 256..511)^T
    unsigned short* w2t   = wts + 393216;           // [512,768]
    unsigned short* w3t   = wts + 786432;           // [256,512]
    unsigned short* cwt   = wts + 917504;           // 16 x [256,256]
    unsigned short* wqkvt = wts + 1966080;          // [768,256]
    unsigned short* wot   = wts + 2162688;          // [256,256]

    // ---- d_out overlays (out region, dead before hidf write at conv-L4) ----
    unsigned short* neb = (unsigned short*)d_out;                       // 10.24 MB
    float*          Pf  = (float*)((char*)d_out + 10240000);            // 61.44 MB
    float*          hidf = (float*)d_out;                               // f32 hid master

    // ---- weight transpose/convert + bias concat ----
    wtrans_kernel<<<dim3(24, 8, 1), 256, 0, stream>>>(em_w1, w1pt, 256, 768, 0, 0);
    wtrans_kernel<<<dim3(24, 8, 1), 256, 0, stream>>>(em_w1 + 196608, w1qt, 256, 768, 0, 0);
    wtrans_kernel<<<dim3(16, 24, 1), 256, 0, stream>>>(em_w2, w2t, 768, 512, 0, 0);
    wtrans_kernel<<<dim3(8, 16, 1), 256, 0, stream>>>(em_w3, w3t, 512, 256, 0, 0);
    wtrans_kernel<<<dim3(8, 8, 16), 256, 0, stream>>>(conv_w, cwt, 256, 256, 65536, 65536);
    wtrans_kernel<<<dim3(8, 8, 1), 256, 0, stream>>>(wq, wqkvt,          256, 256, 0, 0);
    wtrans_kernel<<<dim3(8, 8, 1), 256, 0, stream>>>(wk, wqkvt + 65536,  256, 256, 0, 0);
    wtrans_kernel<<<dim3(8, 8, 1), 256, 0, stream>>>(wv, wqkvt + 131072, 256, 256, 0, 0);
    wtrans_kernel<<<dim3(8, 8, 1), 256, 0, stream>>>(wo, wot, 256, 256, 0, 0);
    concat_bias<<<1, 768, 0, stream>>>(bq, bk, bv, bias768);

    ne_kernel<<<(N_NODES * 64 + 255) / 256, 256, 0, stream>>>(h, nc_w, nc_b, neb);

    hipMemsetAsync(cnt, 0, T_TYPES * N_NODES * 4, stream);
    gine_hist<<<(T_TYPES * EK_EDGES) / 256, 256, 0, stream>>>(eidx, emask, cnt, slots);

    // ---- P/Q projections (f32): ne @ W1_top / W1_bot over 20000 nodes ----
    mfma_gemm<<<dim3(6, 157), 512, 0, stream>>>(neb, 256, 0, w1pt, 0, nullptr, 0,
        nullptr, 0, 0, nullptr, 0, 0, Pf, nullptr, 768, 0, N_NODES, 256, 768, 0);
    mfma_gemm<<<dim3(6, 157), 512, 0, stream>>>(neb, 256, 0, w1qt, 0, nullptr, 0,
        nullptr, 0, 0, nullptr, 0, 0, Qf, nullptr, 768, 0, N_NODES, 256, 768, 0);

    // ---- edge MLP: y1 (elementwise) -> G2 -> G3, 4 chunks of 40000 ----
    for (int c = 0; c < E_EDGES / CH_EDGE; c++) {
        int base = c * CH_EDGE;
        y1_kernel<<<(CH_EDGE * 96) / 256, 256, 0, stream>>>(Pf, Qf, em_b1, eidx, base, y1);
        mfma_gemm<<<dim3(4, 313), 512, 0, stream>>>(y1, 768, 0, w2t, 0, em_b2, 0,
            nullptr, 0, 0, nullptr, 0, 0, nullptr, ch2, 512, 0, CH_EDGE, 768, 512, 1);
        mfma_gemm<<<dim3(2, 313), 512, 0, stream>>>(ch2, 512, 0, w3t, 0, em_b3, 0,
            nullptr, 0, 0, nullptr, 0, 0, mij + (size_t)base * 256, nullptr, 256, 0,
            CH_EDGE, 512, 256, 0);
    }

    // ---- GINE gather: z = xb + sum silu(h[src]+mij), f32+bf16 ----
    gine_gather<<<T_TYPES * N_NODES / 4, 256, 0, stream>>>(h, mij, eidx, cnt, slots, zf, zb);

    // ---- conv MLP: 4 residual layers, type pairs (grid.z=2); L4 fuses hid ----
    for (int p = 0; p < 2; p++) {
        unsigned short* zbp = zb + (size_t)p * 10240000;
        float*          zfp = zf + (size_t)p * 10240000;
        float*          p2f = (float*)(w + (size_t)p * 40960000);
        unsigned short* p2b = (unsigned short*)(w + 81920000 + (size_t)p * 20480000);
        const unsigned short* cw = cwt + (size_t)p * 8 * 65536;
        const float* cb = conv_b + (size_t)p * 8 * 256;
        long tb = (size_t)p * 2 * 256;       // element offset for t = 2p
        dim3 gz(2, 157, 2);
        mfma_gemm<<<gz, 512, 0, stream>>>(zbp, 256, 5120000, cw,            262144, cb,       1024,
            zfp, 256, 5120000, nullptr, 0, 0, p1f, p1b, 256, 5120000, N_NODES, 256, 256, 1);
        mfma_gemm<<<gz, 512, 0, stream>>>(p1b, 256, 5120000, cw + 65536,   262144, cb + 256, 1024,
            p1f, 256, 5120000, nullptr, 0, 0, p2f, p2b, 256, 5120000, N_NODES, 256, 256, 1);
        mfma_gemm<<<gz, 512, 0, stream>>>(p2b, 256, 5120000, cw + 131072,  262144, cb + 512, 1024,
            p2f, 256, 5120000, nullptr, 0, 0, p1f, p1b, 256, 5120000, N_NODES, 256, 256, 1);
        // L4: v = acc + b + p1f;  hid = silu(v) + h  -> hidf f32 + hidb bf16
        mfma_gemm<<<gz, 512, 0, stream>>>(p1b, 256, 5120000, cw + 196608,  262144, cb + 768, 1024,
            p1f, 256, 5120000, h + tb, 1024, 256,
            hidf + tb, hidb + tb, 1024, 256, N_NODES, 256, 256, 0);
    }

    // ---- fused QKV projection -> interleaved qkv [80000,768] bf16 ----
    // A = hidb with lda=256: hidb layout [n*4+t][256] == rows of 80000x256.
    mfma_gemm<<<dim3(6, 625), 512, 0, stream>>>(hidb, 256, 0, wqkvt, 0, bias768, 0,
        nullptr, 0, 0, nullptr, 0, 0, nullptr, qkv, 768, 0, 80000, 256, 768, 0);

    attn_core<<<N_NODES / 2, 256, 0, stream>>>(qkv);

    // ---- output projection + f32 residual, in-place over hidf ----
    mfma_gemm<<<dim3(2, 625), 512, 0, stream>>>(qkv, 768, 0, wot, 0, bo, 0,
        hidf, 256, 0, nullptr, 0, 0, out, nullptr, 256, 0, 80000, 256, 256, 0);
}

// Round 19
// 1737.750 us; speedup vs baseline: 1.1215x; 1.1215x over previous
//
#include <hip/hip_runtime.h>
#include <math.h>

#define N_NODES 20000
#define T_TYPES 4
#define H_DIM   256
#define E_EDGES 160000
#define EK_EDGES 40000
#define CH_EDGE 40000
#define BCAP    32

typedef __attribute__((ext_vector_type(8))) short short8v;
typedef __attribute__((ext_vector_type(8))) unsigned short ushort8v;
typedef __attribute__((ext_vector_type(4))) float f32x4;

__device__ __forceinline__ float silu_f(float x) {
    return x / (1.0f + __expf(-x));
}
__device__ __forceinline__ float b2f(unsigned short u) {
    union { unsigned int i; float f; } v; v.i = ((unsigned int)u) << 16; return v.f;
}
__device__ __forceinline__ unsigned short f2b(float f) {
    union { unsigned int i; float f; } v; v.f = f;
    unsigned int r = v.i + 0x7FFF + ((v.i >> 16) & 1);
    return (unsigned short)(r >> 16);
}

#if __has_builtin(__builtin_amdgcn_global_load_lds)
#define HAS_GLL 1
#define GLOAD16(g, l) __builtin_amdgcn_global_load_lds( \
    (const __attribute__((address_space(1))) void*)(g), \
    (__attribute__((address_space(3))) void*)(l), 16, 0, 0)
#else
#define HAS_GLL 0
#endif

// ---------------- weight transpose+convert: W [K,N] f32 -> Wt [N,K] bf16 -----
__global__ __launch_bounds__(256) void wtrans_kernel(const float* __restrict__ W,
    unsigned short* __restrict__ Wt, int K, int N, long sW, long sWt)
{
    __shared__ float tile[32][33];
    const float* Wz = W + (size_t)blockIdx.z * sW;
    unsigned short* Wtz = Wt + (size_t)blockIdx.z * sWt;
    int tx = threadIdx.x & 31, ty = threadIdx.x >> 5;
    #pragma unroll
    for (int r = ty; r < 32; r += 8) {
        int gr = blockIdx.y * 32 + r, gc = blockIdx.x * 32 + tx;
        tile[r][tx] = Wz[(size_t)gr * N + gc];
    }
    __syncthreads();
    #pragma unroll
    for (int r = ty; r < 32; r += 8) {
        int gn = blockIdx.x * 32 + r, gk = blockIdx.y * 32 + tx;
        Wtz[(size_t)gn * K + gk] = f2b(tile[tx][r]);
    }
}

// ---------------- concat q/k/v biases into one f32[768] ----------------------
__global__ void concat_bias(const float* __restrict__ bq, const float* __restrict__ bk,
    const float* __restrict__ bv, float* __restrict__ b768)
{
    int i = threadIdx.x;
    b768[i] = (i < 256) ? bq[i] : (i < 512 ? bk[i - 256] : bv[i - 512]);
}

// ---------------- node_emb -> bf16 ------------------------------------------
__global__ __launch_bounds__(256) void ne_kernel(const float* __restrict__ h,
    const float* __restrict__ nc_w, const float* __restrict__ nc_b,
    unsigned short* __restrict__ neb)
{
    int idx = blockIdx.x * 256 + threadIdx.x;         // per 4 features
    if (idx >= N_NODES * 64) return;
    int n = idx >> 6, f4 = (idx & 63) * 4;
    const float* hp = h + (size_t)n * 1024 + f4;
    float4 a = *(const float4*)hp;
    float4 b = *(const float4*)(hp + 256);
    float4 c = *(const float4*)(hp + 512);
    float4 d = *(const float4*)(hp + 768);
    float w0 = nc_w[0], w1 = nc_w[1], w2 = nc_w[2], w3 = nc_w[3], bb = nc_b[0];
    ushort4 o;
    o.x = f2b(a.x * w0 + b.x * w1 + c.x * w2 + d.x * w3 + bb);
    o.y = f2b(a.y * w0 + b.y * w1 + c.y * w2 + d.y * w3 + bb);
    o.z = f2b(a.z * w0 + b.z * w1 + c.z * w2 + d.z * w3 + bb);
    o.w = f2b(a.w * w0 + b.w * w1 + c.w * w2 + d.w * w3 + bb);
    *(ushort4*)(neb + (size_t)n * 256 + f4) = o;
}

// ---------------- y1 = silu(P[src] + Q[tgt] + b1), P/Q f32 -> y1 bf16 --------
__global__ __launch_bounds__(256) void y1_kernel(const float* __restrict__ P,
    const float* __restrict__ Q, const float* __restrict__ b1,
    const int* __restrict__ eidx, int base, unsigned short* __restrict__ y1)
{
    int idx = blockIdx.x * 256 + threadIdx.x;       // per 8 outputs
    int row = idx / 96, g = idx - row * 96;         // 768/8 = 96 groups
    int e = base + row;
    int src = eidx[e], tgt = eidx[E_EDGES + e];
    const float* pp = P + (size_t)src * 768 + g * 8;
    const float* qq = Q + (size_t)tgt * 768 + g * 8;
    float4 pa = *(const float4*)pp, pb4 = *(const float4*)(pp + 4);
    float4 qa = *(const float4*)qq, qb4 = *(const float4*)(qq + 4);
    float4 ba = *(const float4*)(b1 + g * 8), bb4 = *(const float4*)(b1 + g * 8 + 4);
    ushort8v o;
    o[0] = f2b(silu_f(pa.x + qa.x + ba.x));
    o[1] = f2b(silu_f(pa.y + qa.y + ba.y));
    o[2] = f2b(silu_f(pa.z + qa.z + ba.z));
    o[3] = f2b(silu_f(pa.w + qa.w + ba.w));
    o[4] = f2b(silu_f(pb4.x + qb4.x + bb4.x));
    o[5] = f2b(silu_f(pb4.y + qb4.y + bb4.y));
    o[6] = f2b(silu_f(pb4.z + qb4.z + bb4.z));
    o[7] = f2b(silu_f(pb4.w + qb4.w + bb4.w));
    *(ushort8v*)(y1 + (size_t)row * 768 + g * 8) = o;
}

// ---------------- bf16 MFMA GEMM (8-wave / 512 threads, 32-AGPR acc) ---------
// R14 configuration (measured optimum, 1740 us): 8 waves per 128x128 tile,
// wave = 32x64 sub-tile -> acc[2][4] = 32 AGPR. launch_bounds(512,6) -> ~72
// combined regs/wave, 3 blocks/CU. 2-slot counted-vmcnt loop; staging =
// 1 A-load + 1 B-load per thread; vmcnt(2). 2 slots x 16 KB = 32 KB LDS.
__global__ __launch_bounds__(512, 6) void mfma_gemm(
    const unsigned short* __restrict__ A, long lda, long zsA,
    const unsigned short* __restrict__ Bt, long zsW,
    const float* __restrict__ bias, long zsBias,
    const float* __restrict__ Rf, long ldr, long zsR,
    float* __restrict__ Cf, unsigned short* __restrict__ Cb, long ldc, long zsC,
    int M, int K, int Nc, int act)
{
    // 2 slots x (A 4096 + B 4096 ushorts) = 32 KB; epilogue [32][136] aliases slot0
    __shared__ unsigned short smem[16384];

    int tid = threadIdx.x;
    int wid = tid >> 6, lane = tid & 63;
    int wr = wid >> 1, wc = wid & 1;                // wave sub-tile (32r x 64c)

    // bijective XCD-chunked swizzle (m204)
    int nwg = gridDim.x * gridDim.y;
    int lin = blockIdx.y * gridDim.x + blockIdx.x;
    int q = nwg >> 3, r8 = nwg & 7, xcd = lin & 7, jj = lin >> 3;
    int g = (xcd < r8 ? xcd * (q + 1) : r8 * (q + 1) + (xcd - r8) * q) + jj;
    int row0 = (g / gridDim.x) * 128, col0 = (g % gridDim.x) * 128;

    int z = blockIdx.z;
    const unsigned short* Btz = Bt + (size_t)z * zsW;
    const float* biasz = bias ? bias + (size_t)z * zsBias : nullptr;
    const float* Rfz = Rf ? Rf + (size_t)z * zsR : nullptr;
    float* Cfz = Cf ? Cf + (size_t)z * zsC : nullptr;
    unsigned short* Cbz = Cb ? Cb + (size_t)z * zsC : nullptr;

    int kb = tid >> 7;                              // k-chunk 0..3 (8 elems each)
    int idx = tid & 127;                            // row (A) / col (B)

    const unsigned short* Ag0 = A + (size_t)z * zsA + (size_t)(row0 + idx) * lda + kb * 8;
    const unsigned short* Bg0 = Btz + (size_t)(col0 + idx) * K + kb * 8;

    f32x4 acc[2][4];
    #pragma unroll
    for (int i = 0; i < 2; i++)
        #pragma unroll
        for (int j = 0; j < 4; j++)
            acc[i][j] = (f32x4){0.f, 0.f, 0.f, 0.f};

    int nt = K / 32;
    int lds_dst = kb * 1024 + idx * 8;              // [kb][idx][8]

#if HAS_GLL
#define STAGE(s, k0) do { \
    GLOAD16(Ag0 + (k0), &smem[(s) * 8192 + lds_dst]); \
    GLOAD16(Bg0 + (k0), &smem[(s) * 8192 + 4096 + lds_dst]); \
} while (0)

    STAGE(0, 0);
    for (int t = 0; t < nt; ++t) {
        if (t + 1 < nt) {
            STAGE((t + 1) & 1, (t + 1) * 32);
            asm volatile("s_waitcnt vmcnt(2)" ::: "memory");
        } else {
            asm volatile("s_waitcnt vmcnt(0)" ::: "memory");
        }
        __builtin_amdgcn_sched_barrier(0);
        __builtin_amdgcn_s_barrier();
        __builtin_amdgcn_sched_barrier(0);
        const unsigned short* Asb = &smem[(t & 1) * 8192];
        const unsigned short* Bsb = Asb + 4096;
        short8v af[2], bfr[4];
        int kb4 = (lane >> 4) * 1024;
        int lr = lane & 15;
        #pragma unroll
        for (int mi = 0; mi < 2; mi++)
            af[mi] = *(const short8v*)&Asb[kb4 + (wr * 32 + mi * 16 + lr) * 8];
        #pragma unroll
        for (int ni = 0; ni < 4; ni++)
            bfr[ni] = *(const short8v*)&Bsb[kb4 + (wc * 64 + ni * 16 + lr) * 8];
        #pragma unroll
        for (int mi = 0; mi < 2; mi++)
            #pragma unroll
            for (int ni = 0; ni < 4; ni++)
                acc[mi][ni] = __builtin_amdgcn_mfma_f32_16x16x32_bf16(
                    af[mi], bfr[ni], acc[mi][ni], 0, 0, 0);
        // trailing barrier: protects slot (t&1) from iter t+2's STAGE overwrite
        __builtin_amdgcn_sched_barrier(0);
        __builtin_amdgcn_s_barrier();
        __builtin_amdgcn_sched_barrier(0);
    }
#undef STAGE
#else
    for (int t = 0; t < nt; ++t) {
        int k0 = t * 32;
        __syncthreads();
        *(ushort8v*)&smem[lds_dst] = *(const ushort8v*)(Ag0 + k0);
        *(ushort8v*)&smem[4096 + lds_dst] = *(const ushort8v*)(Bg0 + k0);
        __syncthreads();
        short8v af[2], bfr[4];
        int kb4 = (lane >> 4) * 1024;
        int lr = lane & 15;
        #pragma unroll
        for (int mi = 0; mi < 2; mi++)
            af[mi] = *(const short8v*)&smem[kb4 + (wr * 32 + mi * 16 + lr) * 8];
        #pragma unroll
        for (int ni = 0; ni < 4; ni++)
            bfr[ni] = *(const short8v*)&smem[4096 + kb4 + (wc * 64 + ni * 16 + lr) * 8];
        #pragma unroll
        for (int mi = 0; mi < 2; mi++)
            #pragma unroll
            for (int ni = 0; ni < 4; ni++)
                acc[mi][ni] = __builtin_amdgcn_mfma_f32_16x16x32_bf16(
                    af[mi], bfr[ni], acc[mi][ni], 0, 0, 0);
    }
    __syncthreads();
#endif

    if (Cbz) {
        // bf16 output via LDS transpose -> ushort8 coalesced stores.
        // 4 row-groups of 32; group rg filled by the two waves with wr==rg,
        // then all 512 threads copy out 32 rows x 128 cols (1 ushort8 each).
        #pragma unroll
        for (int rg = 0; rg < 4; rg++) {
            __syncthreads();
            if (wr == rg) {
                #pragma unroll
                for (int ni = 0; ni < 4; ni++) {
                    int col = wc * 64 + ni * 16 + (lane & 15);
                    float bv = biasz ? biasz[col0 + col] : 0.f;
                    #pragma unroll
                    for (int mi = 0; mi < 2; mi++) {
                        #pragma unroll
                        for (int rr = 0; rr < 4; rr++) {
                            int lrow = mi * 16 + (lane >> 4) * 4 + rr;   // 0..31
                            int grow = row0 + rg * 32 + lrow;
                            float v = acc[mi][ni][rr] + bv;
                            if (act) v = silu_f(v);
                            if (grow < M) {
                                size_t off = (size_t)grow * ldc + col0 + col;
                                if (Rfz) v += Rfz[(size_t)grow * ldr + col0 + col];
                                if (Cfz) Cfz[off] = v;
                            }
                            smem[lrow * 136 + col] = f2b(v);
                        }
                    }
                }
            }
            __syncthreads();
            int rrow = tid >> 4, grp = tid & 15;
            int grow = row0 + rg * 32 + rrow;
            if (grow < M)
                *(ushort8v*)(Cbz + (size_t)grow * ldc + col0 + grp * 8) =
                    *(const ushort8v*)&smem[rrow * 136 + grp * 8];
        }
    } else {
        #pragma unroll
        for (int ni = 0; ni < 4; ni++) {
            int col = col0 + wc * 64 + ni * 16 + (lane & 15);
            float bv = biasz ? biasz[col] : 0.f;
            #pragma unroll
            for (int mi = 0; mi < 2; mi++) {
                #pragma unroll
                for (int rr = 0; rr < 4; rr++) {
                    int grow = row0 + wr * 32 + mi * 16 + (lane >> 4) * 4 + rr;
                    if (grow < M) {
                        float v = acc[mi][ni][rr] + bv;
                        if (act) v = silu_f(v);
                        size_t off = (size_t)grow * ldc + col;
                        if (Rfz) v += Rfz[(size_t)grow * ldr + col];
                        Cfz[off] = v;
                    }
                }
            }
        }
    }
}

// ---------------- GINE bucket build: cnt/slots keyed by (t, dst) -------------
__global__ __launch_bounds__(256) void gine_hist(const int* __restrict__ eidx,
    const int* __restrict__ emask, int* __restrict__ cnt, int* __restrict__ slots)
{
    int idx = blockIdx.x * 256 + threadIdx.x;       // [0, T*EK)
    int t = idx / EK_EDGES;
    int em = emask[idx];
    int dst = eidx[E_EDGES + em];
    int tn = t * N_NODES + dst;
    int pos = atomicAdd(&cnt[tn], 1);
    if (pos < BCAP) slots[tn * BCAP + pos] = em;
}

// ---------------- GINE gather: z[t,n,:] = xb + sum silu(h[src]+mij[em]) ------
__global__ __launch_bounds__(256) void gine_gather(
    const float* __restrict__ h, const float* __restrict__ mij,
    const int* __restrict__ eidx, const int* __restrict__ cnt,
    const int* __restrict__ slots, float* __restrict__ zf,
    unsigned short* __restrict__ zb)
{
    int tn = blockIdx.x * 4 + (threadIdx.x >> 6);
    int lane = threadIdx.x & 63;
    int t = tn / N_NODES, n = tn - t * N_NODES;
    int f = lane * 4;
    int deg = cnt[tn]; if (deg > BCAP) deg = BCAP;
    float4 acc = *(const float4*)(h + (size_t)n * 1024 + t * 256 + f);   // xb
    for (int j = 0; j < deg; j++) {
        int em = slots[tn * BCAP + j];
        int src = eidx[em];
        float4 hv = *(const float4*)(h + (size_t)src * 1024 + t * 256 + f);
        float4 mv = *(const float4*)(mij + (size_t)em * 256 + f);
        acc.x += silu_f(hv.x + mv.x);
        acc.y += silu_f(hv.y + mv.y);
        acc.z += silu_f(hv.z + mv.z);
        acc.w += silu_f(hv.w + mv.w);
    }
    *(float4*)(zf + (size_t)tn * 256 + f) = acc;
    ushort4 o;
    o.x = f2b(acc.x); o.y = f2b(acc.y); o.z = f2b(acc.z); o.w = f2b(acc.w);
    *(ushort4*)(zb + (size_t)tn * 256 + f) = o;
}

// ---------------- hid: f32 master + bf16 copy, layout [n*4+t, f] -------------
__global__ __launch_bounds__(256) void hid_kernel(const float* __restrict__ h,
    const float* __restrict__ zf, float* __restrict__ hidf,
    unsigned short* __restrict__ hidb)
{
    int idx = blockIdx.x * 256 + threadIdx.x;        // per 4 features
    if (idx >= N_NODES * T_TYPES * 64) return;
    int nt = idx >> 6, f4 = (idx & 63) * 4;
    int n = nt >> 2, t = nt & 3;
    float4 zv = *(const float4*)(zf + ((size_t)t * N_NODES + n) * 256 + f4);
    float4 hv = *(const float4*)(h + (size_t)nt * 256 + f4);
    float4 o;
    o.x = silu_f(zv.x) + hv.x; o.y = silu_f(zv.y) + hv.y;
    o.z = silu_f(zv.z) + hv.z; o.w = silu_f(zv.w) + hv.w;
    *(float4*)(hidf + (size_t)nt * 256 + f4) = o;
    ushort4 ob;
    ob.x = f2b(o.x); ob.y = f2b(o.y); ob.z = f2b(o.z); ob.w = f2b(o.w);
    *(ushort4*)(hidb + (size_t)nt * 256 + f4) = ob;
}

// ---------------- attention core on interleaved qkv [80000, 768] bf16 --------
__global__ __launch_bounds__(256) void attn_core(unsigned short* __restrict__ qkv)
{
    int tid = threadIdx.x;
    int n = blockIdx.x * 2 + (tid >> 7);
    int local = tid & 127, hh = local >> 2, i = local & 3;
    size_t rb = (size_t)n * 4 * 768;
    size_t qoff = rb + (size_t)i * 768 + hh * 8;
    ushort8v qv = *(const ushort8v*)(qkv + qoff);
    float q[8];
    #pragma unroll
    for (int d = 0; d < 8; d++) q[d] = b2f(qv[d]);
    const float scale = 0.35355339059327373f;   // 1/sqrt(8)
    float s[4];
    #pragma unroll
    for (int j = 0; j < 4; j++) {
        ushort8v kv = *(const ushort8v*)(qkv + rb + (size_t)j * 768 + 256 + hh * 8);
        float acc = 0.f;
        #pragma unroll
        for (int d = 0; d < 8; d++) acc += q[d] * b2f(kv[d]);
        s[j] = acc * scale;
    }
    float m = fmaxf(fmaxf(s[0], s[1]), fmaxf(s[2], s[3]));
    float e[4], sum = 0.f;
    #pragma unroll
    for (int j = 0; j < 4; j++) { e[j] = __expf(s[j] - m); sum += e[j]; }
    float inv = 1.0f / sum;
    float o[8] = {};
    #pragma unroll
    for (int j = 0; j < 4; j++) {
        ushort8v vv = *(const ushort8v*)(qkv + rb + (size_t)j * 768 + 512 + hh * 8);
        float p = e[j] * inv;
        #pragma unroll
        for (int d = 0; d < 8; d++) o[d] += p * b2f(vv[d]);
    }
    ushort8v ov;
    #pragma unroll
    for (int d = 0; d < 8; d++) ov[d] = f2b(o[d]);
    *(ushort8v*)(qkv + qoff) = ov;
}

// =============================================================================
extern "C" void kernel_launch(void* const* d_in, const int* in_sizes, int n_in,
                              void* d_out, int out_size, void* d_ws, size_t ws_size,
                              hipStream_t stream)
{
    (void)in_sizes; (void)n_in; (void)out_size; (void)ws_size;
    const float* h     = (const float*)d_in[0];
    const int*   eidx  = (const int*)d_in[1];
    const int*   emask = (const int*)d_in[2];
    const float* nc_w  = (const float*)d_in[3];
    const float* nc_b  = (const float*)d_in[4];
    const float* em_w1 = (const float*)d_in[5];
    const float* em_b1 = (const float*)d_in[6];
    const float* em_w2 = (const float*)d_in[7];
    const float* em_b2 = (const float*)d_in[8];
    const float* em_w3 = (const float*)d_in[9];
    const float* em_b3 = (const float*)d_in[10];
    const float* conv_w = (const float*)d_in[11];
    const float* conv_b = (const float*)d_in[12];
    const float* wq = (const float*)d_in[13]; const float* bq = (const float*)d_in[14];
    const float* wk = (const float*)d_in[15]; const float* bk = (const float*)d_in[16];
    const float* wv = (const float*)d_in[17]; const float* bv = (const float*)d_in[18];
    const float* wo = (const float*)d_in[19]; const float* bo = (const float*)d_in[20];

    float* out = (float*)d_out;                                   // [80000,256] f32
    float* mij = out + (size_t)20480000;                          // [160000,256] f32

    // ---- workspace arena (bytes); peak 188.78 MB (R10-R14-proven layout) ----
    char* w = (char*)d_ws;
    // edge phase
    unsigned short* y1  = (unsigned short*)w;                     // [0, 61.44M)
    unsigned short* ch2 = (unsigned short*)(w + 61440000);        // [61.44M, 102.4M)
    float*          Qf  = (float*)(w + 102400000);                // [102.4M, 163.84M)
    int*            cnt   = (int*)(w + 163840000);                // [163.84M, 164.16M)
    int*            slots = (int*)(w + 164160000);                // [164.16M, 174.4M)
    // GINE / conv phase (cnt/slots consumed by gine_gather before conv writes)
    float*          zf  = (float*)w;                              // [0, 81.92M)
    unsigned short* zb  = (unsigned short*)(w + 81920000);        // [81.92M, 122.88M)
    float*          p1f = (float*)(w + 122880000);                // [122.88M, 163.84M)
    unsigned short* p1b = (unsigned short*)(w + 163840000);       // [163.84M, 184.32M)
    // persistent weights
    unsigned short* wts = (unsigned short*)(w + 184320000);       // 4.46 MB
    float*          bias768 = (float*)(w + 188780032);            // 3 KB
    // attention phase
    unsigned short* hidb = (unsigned short*)(w + 122880000);      // 41 MB (over p1f)
    unsigned short* qkv  = (unsigned short*)w;                    // 122.88 MB (over zf/zb)

    unsigned short* w1pt  = wts;                    // [768,256]  (W1 rows 0..255)^T
    unsigned short* w1qt  = wts + 196608;           // [768,256]  (W1 rows 256..511)^T
    unsigned short* w2t   = wts + 393216;           // [512,768]
    unsigned short* w3t   = wts + 786432;           // [256,512]
    unsigned short* cwt   = wts + 917504;           // 16 x [256,256]
    unsigned short* wqkvt = wts + 1966080;          // [768,256]
    unsigned short* wot   = wts + 2162688;          // [256,256]

    // ---- d_out overlays (out region, dead before hidf write) ----
    unsigned short* neb = (unsigned short*)d_out;                       // 10.24 MB
    float*          Pf  = (float*)((char*)d_out + 10240000);            // 61.44 MB
    float*          hidf = (float*)d_out;                               // f32 hid master

    // ---- weight transpose/convert + bias concat ----
    wtrans_kernel<<<dim3(24, 8, 1), 256, 0, stream>>>(em_w1, w1pt, 256, 768, 0, 0);
    wtrans_kernel<<<dim3(24, 8, 1), 256, 0, stream>>>(em_w1 + 196608, w1qt, 256, 768, 0, 0);
    wtrans_kernel<<<dim3(16, 24, 1), 256, 0, stream>>>(em_w2, w2t, 768, 512, 0, 0);
    wtrans_kernel<<<dim3(8, 16, 1), 256, 0, stream>>>(em_w3, w3t, 512, 256, 0, 0);
    wtrans_kernel<<<dim3(8, 8, 16), 256, 0, stream>>>(conv_w, cwt, 256, 256, 65536, 65536);
    wtrans_kernel<<<dim3(8, 8, 1), 256, 0, stream>>>(wq, wqkvt,          256, 256, 0, 0);
    wtrans_kernel<<<dim3(8, 8, 1), 256, 0, stream>>>(wk, wqkvt + 65536,  256, 256, 0, 0);
    wtrans_kernel<<<dim3(8, 8, 1), 256, 0, stream>>>(wv, wqkvt + 131072, 256, 256, 0, 0);
    wtrans_kernel<<<dim3(8, 8, 1), 256, 0, stream>>>(wo, wot, 256, 256, 0, 0);
    concat_bias<<<1, 768, 0, stream>>>(bq, bk, bv, bias768);

    ne_kernel<<<(N_NODES * 64 + 255) / 256, 256, 0, stream>>>(h, nc_w, nc_b, neb);

    hipMemsetAsync(cnt, 0, T_TYPES * N_NODES * 4, stream);
    gine_hist<<<(T_TYPES * EK_EDGES) / 256, 256, 0, stream>>>(eidx, emask, cnt, slots);

    // ---- P/Q projections (f32): ne @ W1_top / W1_bot over 20000 nodes ----
    mfma_gemm<<<dim3(6, 157), 512, 0, stream>>>(neb, 256, 0, w1pt, 0, nullptr, 0,
        nullptr, 0, 0, Pf, nullptr, 768, 0, N_NODES, 256, 768, 0);
    mfma_gemm<<<dim3(6, 157), 512, 0, stream>>>(neb, 256, 0, w1qt, 0, nullptr, 0,
        nullptr, 0, 0, Qf, nullptr, 768, 0, N_NODES, 256, 768, 0);

    // ---- edge MLP: y1 (elementwise) -> G2 -> G3, 4 chunks of 40000 ----
    for (int c = 0; c < E_EDGES / CH_EDGE; c++) {
        int base = c * CH_EDGE;
        y1_kernel<<<(CH_EDGE * 96) / 256, 256, 0, stream>>>(Pf, Qf, em_b1, eidx, base, y1);
        mfma_gemm<<<dim3(4, 313), 512, 0, stream>>>(y1, 768, 0, w2t, 0, em_b2, 0,
            nullptr, 0, 0, nullptr, ch2, 512, 0, CH_EDGE, 768, 512, 1);
        mfma_gemm<<<dim3(2, 313), 512, 0, stream>>>(ch2, 512, 0, w3t, 0, em_b3, 0,
            nullptr, 0, 0, mij + (size_t)base * 256, nullptr, 256, 0,
            CH_EDGE, 512, 256, 0);
    }

    // ---- GINE gather: z = xb + sum silu(h[src]+mij), f32+bf16 ----
    gine_gather<<<T_TYPES * N_NODES / 4, 256, 0, stream>>>(h, mij, eidx, cnt, slots, zf, zb);

    // ---- conv MLP: 4 residual layers, type-batched in pairs (grid.z=2) ----
    for (int p = 0; p < 2; p++) {
        unsigned short* zbp = zb + (size_t)p * 10240000;
        float*          zfp = zf + (size_t)p * 10240000;
        float*          p2f = (float*)(w + (size_t)p * 40960000);
        unsigned short* p2b = (unsigned short*)(w + 81920000 + (size_t)p * 20480000);
        const unsigned short* cw = cwt + (size_t)p * 8 * 65536;
        const float* cb = conv_b + (size_t)p * 8 * 256;
        dim3 gz(2, 157, 2);
        mfma_gemm<<<gz, 512, 0, stream>>>(zbp, 256, 5120000, cw,            262144, cb,       1024,
            zfp, 256, 5120000, p1f, p1b, 256, 5120000, N_NODES, 256, 256, 1);
        mfma_gemm<<<gz, 512, 0, stream>>>(p1b, 256, 5120000, cw + 65536,   262144, cb + 256, 1024,
            p1f, 256, 5120000, p2f, p2b, 256, 5120000, N_NODES, 256, 256, 1);
        mfma_gemm<<<gz, 512, 0, stream>>>(p2b, 256, 5120000, cw + 131072,  262144, cb + 512, 1024,
            p2f, 256, 5120000, p1f, p1b, 256, 5120000, N_NODES, 256, 256, 1);
        mfma_gemm<<<gz, 512, 0, stream>>>(p1b, 256, 5120000, cw + 196608,  262144, cb + 768, 1024,
            p1f, 256, 5120000, zfp, nullptr, 256, 5120000, N_NODES, 256, 256, 0);
    }

    // ---- hid: f32 master in d_out + bf16 copy ----
    hid_kernel<<<(N_NODES * T_TYPES * 64) / 256, 256, 0, stream>>>(h, zf, hidf, hidb);

    // ---- fused QKV projection -> interleaved qkv [80000,768] bf16 ----
    mfma_gemm<<<dim3(6, 625), 512, 0, stream>>>(hidb, 256, 0, wqkvt, 0, bias768, 0,
        nullptr, 0, 0, nullptr, qkv, 768, 0, 80000, 256, 768, 0);

    attn_core<<<N_NODES / 2, 256, 0, stream>>>(qkv);

    // ---- output projection + f32 residual, in-place over hidf ----
    mfma_gemm<<<dim3(2, 625), 512, 0, stream>>>(qkv, 768, 0, wot, 0, bo, 0,
        hidf, 256, 0, out, nullptr, 256, 0, 80000, 256, 256, 0);
}